// Round 7
// baseline (208.779 us; speedup 1.0000x reference)
//
#include <hip/hip_runtime.h>
#include <math.h>

#define D_MODEL 512
#define SEQ     4096
#define BATCH   4
#define BS      (BATCH * SEQ)  // 16384

typedef __attribute__((ext_vector_type(8))) short  short8;   // 8 x bf16 (4 VGPRs)
typedef __attribute__((ext_vector_type(4))) float  float4v;  // MFMA C/D

#define GAS __attribute__((address_space(1)))
#define LAS __attribute__((address_space(3)))

__device__ __forceinline__ void gld_lds16(const void* g, void* l) {
  __builtin_amdgcn_global_load_lds((const GAS unsigned int*)g,
                                   (LAS unsigned int*)l, 16, 0, 0);
}

__device__ __forceinline__ unsigned short bf16r(float f) {
  unsigned int u = __builtin_bit_cast(unsigned int, f);
  u += 0x7fffu + ((u >> 16) & 1u);  // RTNE
  return (unsigned short)(u >> 16);
}

__device__ __forceinline__ uint4 pack8(float4 a, float4 b) {
  uint4 o;
  o.x = bf16r(a.x) | ((unsigned)bf16r(a.y) << 16);
  o.y = bf16r(a.z) | ((unsigned)bf16r(a.w) << 16);
  o.z = bf16r(b.x) | ((unsigned)bf16r(b.y) << 16);
  o.w = bf16r(b.z) | ((unsigned)bf16r(b.w) << 16);
  return o;
}

// --------------------------------------------------------------------------
// Prep kernel:
//   blocks 0..63   : W_qk [k][n] -> Wqkt [n][k] bf16 (tile transpose)
//   blocks 64..191 : W_v straight convert to bf16
//   blocks 192..255: x fp32 -> xb bf16 (linear, for attn K-reads) AND
//                    xbB (BLOCKED: [mt][slab][256r][64k] with the qv LDS
//                    swizzle pre-baked, contiguous 16KB tiles). One block
//                    per 256-row strip; each thread streams its full 2KB
//                    x row sequentially -> DRAM-page-friendly reads. This
//                    kills qv's 128B-per-1KB-row staging pattern (the
//                    invariant across 4 null rounds; ~1.9 TB/s measured).
// --------------------------------------------------------------------------
__global__ __launch_bounds__(256) void cvt_w(const float* __restrict__ Wqk,
                                             unsigned short* __restrict__ Wqkt,
                                             const float* __restrict__ Wv,
                                             unsigned short* __restrict__ Wvb,
                                             const float* __restrict__ x,
                                             unsigned short* __restrict__ xb,
                                             unsigned short* __restrict__ xbB) {
  if (blockIdx.x < 64) {
    __shared__ float tile[64][65];
    const int bx = blockIdx.x & 7;   // n-tile
    const int by = blockIdx.x >> 3;  // k-tile
    const int tx = threadIdx.x & 63;
    const int ty = threadIdx.x >> 6;
    for (int r = ty; r < 64; r += 4)
      tile[r][tx] = Wqk[(size_t)(by * 64 + r) * D_MODEL + bx * 64 + tx];
    __syncthreads();
    for (int r = ty; r < 64; r += 4)
      Wqkt[(size_t)(bx * 64 + r) * D_MODEL + by * 64 + tx] = bf16r(tile[tx][r]);
  } else if (blockIdx.x < 192) {
    const int idx = ((blockIdx.x - 64) * 256 + threadIdx.x) * 8;
    const float4 a = *(const float4*)(Wv + idx);
    const float4 b = *(const float4*)(Wv + idx + 4);
    *(uint4*)(Wvb + idx) = pack8(a, b);
  } else {
    // x-blocking: mt = bid-192 (256-row strip), thread r = one row.
    const int mt = blockIdx.x - 192;
    const int r  = threadIdx.x;
    const int row = mt * 256 + r;
    const float* xr = x + (size_t)row * D_MODEL;
    const int rk = r & 7;  // swizzle key for this row
#pragma unroll 1
    for (int slab = 0; slab < 8; ++slab) {
      const int k0 = slab * 64;
      float4 f[16];
#pragma unroll
      for (int i = 0; i < 16; ++i) f[i] = *(const float4*)(xr + k0 + i * 4);
      // linear xb (attn K path): cols in order
      uint4 lin[8];
#pragma unroll
      for (int s = 0; s < 8; ++s) lin[s] = pack8(f[s * 2], f[s * 2 + 1]);
#pragma unroll
      for (int s = 0; s < 8; ++s)
        *(uint4*)&xb[(size_t)row * D_MODEL + k0 + s * 8] = lin[s];
      // blocked xbB: chunk s holds source col-group (s ^ rk)
      unsigned short* bb = xbB + (((size_t)(mt * 8 + slab) * 2048) + r * 8) * 8;
#pragma unroll
      for (int s = 0; s < 8; ++s) {
        const int cs = s ^ rk;
        *(uint4*)&bb[s * 8] = lin[cs];
      }
    }
  }
}

// --------------------------------------------------------------------------
// Combined Q+V GEMM: M=16384, N=1024 ([512 Q-cols | 512 V-dims]), K=512.
// BM=BN=256, BK=64, 256 blocks (1/CU) x 512 threads (8 waves, wave-tile
// 64(A) x 128(B)). DOUBLE-buffered LDS (4 x 32 KB = 128 KB) with a
// counted-vmcnt pipeline (T3/T4): raw s_barrier + s_waitcnt vmcnt(8)
// inline asm so each slab's 16-load prefetch stays IN FLIGHT across the
// barrier (the compiler's vmcnt(0)-before-__syncthreads drain was the
// invariant stall of rounds 1-6).
//   Invariant at top of iter s: buf[s&1] staged-complete, buf[(s+1)&1]
//   staging in flight (8 gld/wave). Per iter: compute(cur) -> barrier A
//   (all waves done reading cur) -> stage(cur, s+2) -> vmcnt(8) retires
//   the s+1 prefetch -> barrier B publishes it.
// A staged LINEARLY from xbB (contiguous 16B-chunk stream, swizzle baked);
// B staged from weights (1 MB, L2-resident; stride harmless in SRAM).
// Operand roles per path for tt-contiguous packed uint2 stores:
//   Q (nt<2):  A=W, B=x -> Qb[xrow][Qcol], tt spans Q-cols.
//   V (nt>=2): A=x, B=W -> Vt[dim][key],  tt spans keys.
// --------------------------------------------------------------------------
__global__ __launch_bounds__(512, 2) void qv_gemm(const unsigned short* __restrict__ xbB,
                                                  const unsigned short* __restrict__ Wqkt,
                                                  const unsigned short* __restrict__ Wvb,
                                                  const float* __restrict__ bv,
                                                  unsigned short* __restrict__ Qb,
                                                  unsigned short* __restrict__ Vt,
                                                  float scale) {
  __shared__ unsigned short As[2][256 * 64];  // 2 x 32 KB (x rows)
  __shared__ unsigned short Bs[2][256 * 64];  // 2 x 32 KB (weight rows)

  const int t    = threadIdx.x;
  const int w    = t >> 6;
  const int lane = t & 63;
  const int q    = lane >> 4;
  const int c    = lane & 15;
  const int wr   = w >> 1;   // 0..3: wave's 64-span on the A-side
  const int wc   = w & 1;    // 0..1: wave's 128-span on the B-side
  const int sw   = c & 7;    // read-side swizzle key

  const int mt = blockIdx.x & 63;   // M-tile, fastest -> A-sharers same XCD
  const int nt = blockIdx.x >> 6;   // 0,1 = Q col-tiles; 2,3 = V dim-tiles
  const int a0 = mt * 256;
  const bool vt = (nt >= 2);
  const int b0 = (nt & 1) * 256;
  const unsigned short* __restrict__ Wgt = vt ? Wvb : Wqkt;

  float4v acc[4][8];
#pragma unroll
  for (int i = 0; i < 4; ++i)
#pragma unroll
    for (int j = 0; j < 8; ++j) acc[i][j] = (float4v){0.f, 0.f, 0.f, 0.f};

  auto stage = [&](int buf, int slab) {
    const unsigned short* ab = xbB + (size_t)(mt * 8 + slab) * 16384;
    const int k0 = slab * 64;
#pragma unroll
    for (int it = 0; it < 4; ++it) {
      const int idx = it * 512 + t;  // 0..2047
      // A: fully linear (swizzle pre-baked by cvt)
      gld_lds16(ab + idx * 8, &As[buf][idx * 8]);
      // B: inline source swizzle (L2-resident weights)
      const int r  = idx >> 3;
      const int ss = idx & 7;
      gld_lds16(Wgt + (size_t)(b0 + r) * D_MODEL + k0 + ((ss ^ (r & 7)) << 3),
                &Bs[buf][idx * 8]);
    }
  };

  // prologue: fill buf0, launch buf1, wait only for buf0 (vmcnt 8 = buf1)
  stage(0, 0);
  stage(1, 1);
  asm volatile("s_waitcnt vmcnt(8)" ::: "memory");
  asm volatile("s_barrier" ::: "memory");

#pragma unroll 1
  for (int s = 0; s < 8; ++s) {
    const int cur = s & 1;
    const unsigned short* SA = vt ? As[cur] : Bs[cur];  // A-operand source
    const unsigned short* SB = vt ? Bs[cur] : As[cur];  // B-operand source

#pragma unroll
    for (int kc = 0; kc < 2; ++kc) {
      const int slot = ((kc * 4 + q) ^ sw) * 8;
      short8 af[4], bf[8];
#pragma unroll
      for (int i = 0; i < 4; ++i)
        af[i] = *(const short8*)&SA[(wr * 64 + i * 16 + c) * 64 + slot];
#pragma unroll
      for (int j = 0; j < 8; ++j)
        bf[j] = *(const short8*)&SB[(wc * 128 + j * 16 + c) * 64 + slot];
#pragma unroll
      for (int i = 0; i < 4; ++i)
#pragma unroll
        for (int j = 0; j < 8; ++j)
          acc[i][j] = __builtin_amdgcn_mfma_f32_16x16x32_bf16(af[i], bf[j], acc[i][j], 0, 0, 0);
    }

    asm volatile("s_barrier" ::: "memory");      // A: all waves done with buf[cur]
    if (s + 2 < 8) stage(cur, s + 2);            // refill buf[cur] (in flight)
    if (s + 1 < 8) {
      if (s + 2 < 8) asm volatile("s_waitcnt vmcnt(8)" ::: "memory");  // s+1 done
      else           asm volatile("s_waitcnt vmcnt(0)" ::: "memory");  // drain last
      asm volatile("s_barrier" ::: "memory");    // B: buf[s+1 & 1] published
    }
  }

  if (!vt) {
    // Q: A=W -> Qcol = nt*256 + wr*64 + i*16 + 4q + tt; xrow = a0 + wc*128 + j*16 + c
#pragma unroll
    for (int j = 0; j < 8; ++j) {
      const size_t row = a0 + wc * 128 + j * 16 + c;
#pragma unroll
      for (int i = 0; i < 4; ++i) {
        uint2 pkt;
        pkt.x = (unsigned)bf16r(scale * acc[i][j][0]) |
                ((unsigned)bf16r(scale * acc[i][j][1]) << 16);
        pkt.y = (unsigned)bf16r(scale * acc[i][j][2]) |
                ((unsigned)bf16r(scale * acc[i][j][3]) << 16);
        *(uint2*)&Qb[row * D_MODEL + nt * 256 + wr * 64 + i * 16 + 4 * q] = pkt;
      }
    }
  } else {
    // V: A=x -> key = a0 + wr*64 + i*16 + 4q + tt; dim = (nt-2)*256 + wc*128 + j*16 + c
#pragma unroll
    for (int j = 0; j < 8; ++j) {
      const int dim = (nt - 2) * 256 + wc * 128 + j * 16 + c;
      const float bvv = bv[dim];
#pragma unroll
      for (int i = 0; i < 4; ++i) {
        const int key = a0 + wr * 64 + i * 16 + 4 * q;
        uint2 pkt;
        pkt.x = (unsigned)bf16r(acc[i][j][0] + bvv) |
                ((unsigned)bf16r(acc[i][j][1] + bvv) << 16);
        pkt.y = (unsigned)bf16r(acc[i][j][2] + bvv) |
                ((unsigned)bf16r(acc[i][j][3] + bvv) << 16);
        *(uint2*)&Vt[(size_t)dim * BS + key] = pkt;
      }
    }
  }
}

// --------------------------------------------------------------------------
// Windowed causal ALiBi attention (unchanged). Block = 128 threads (2
// waves) = one 16-query tile; grid = 1024. Window = keys [i0-48, i0+15].
// --------------------------------------------------------------------------
__global__ __launch_bounds__(128) void attn_tile(const unsigned short* __restrict__ Q,
                                                 const unsigned short* __restrict__ Kx,
                                                 const unsigned short* __restrict__ Vt,
                                                 float* __restrict__ out) {
  constexpr int PLD = 72;  // 64 + 8 pad shorts; row stride 144 B (16B-aligned)
  __shared__ unsigned short pls[16 * PLD];  // 2304 B
  __shared__ float lm[2][16], ls[2][16];

  const int t    = threadIdx.x;
  const int h    = t >> 6;
  const int lane = t & 63;
  const int q    = lane >> 4;
  const int c    = lane & 15;

  // XCD-contiguous swizzle: XCD x gets tiles [x*128, (x+1)*128)
  const int tile = ((blockIdx.x & 7) << 7) + (blockIdx.x >> 3);
  const int r0   = tile << 4;           // global query base
  const int b    = r0 >> 12;            // batch
  const int i0   = r0 & (SEQ - 1);      // local query base
  const int jb   = i0 - 48;             // window start (may be < 0)

  // ---- Q fragments: 16 queries x 512 (both waves load the same Q) ----
  short8 qf[16];
  {
    const unsigned short* qp = Q + (size_t)(r0 + c) * D_MODEL + q * 8;
#pragma unroll
    for (int ch = 0; ch < 16; ++ch) qf[ch] = *(const short8*)(qp + ch * 32);
  }

  // ---- S = Q K^T for this wave's 2 subtiles (sj = 2h, 2h+1) ----
  float4v sacc[2];
  sacc[0] = (float4v){0.f, 0.f, 0.f, 0.f};
  sacc[1] = (float4v){0.f, 0.f, 0.f, 0.f};
#pragma unroll
  for (int s = 0; s < 2; ++s) {
    const int sj = 2 * h + s;
    if (jb + 16 * sj + 15 < 0) continue;  // whole subtile below key 0
    int krow = jb + 16 * sj + c;
    if (krow < 0) krow = 0;  // masked below
    const unsigned short* kr = Kx + ((size_t)(b << 12) + krow) * D_MODEL + q * 8;
    float4v sv = sacc[s];
#pragma unroll
    for (int ch = 0; ch < 16; ++ch)
      sv = __builtin_amdgcn_mfma_f32_16x16x32_bf16(qf[ch], *(const short8*)(kr + ch * 32), sv, 0, 0, 0);
    sacc[s] = sv;
  }

  // ---- prefetch V chunk 0 (latency hides under softmax reductions) ----
  const unsigned short* vbase = Vt + (size_t)(h * 256 + c) * BS + (b << 12);
  const bool ch0 = (jb + 31 >= 0);
  short8 vf0[16];
  if (ch0) {
    int kk = jb + q * 8;
    if (kk < 0) kk = 0;  // p == 0 there
    const unsigned short* vb = vbase + kk;
#pragma unroll
    for (int dt = 0; dt < 16; ++dt) vf0[dt] = *(const short8*)(vb + (size_t)dt * 16 * BS);
  }

  // ---- ALiBi + causal/window mask + wave-local row max ----
  float tmax[4] = {-1e30f, -1e30f, -1e30f, -1e30f};
#pragma unroll
  for (int s = 0; s < 2; ++s)
#pragma unroll
    for (int tt = 0; tt < 4; ++tt) {
      const int jl = jb + 16 * (2 * h + s) + c;
      const int il = i0 + 4 * q + tt;
      float sv = sacc[s][tt];
      sv = (jl < 0 || jl > il) ? -1e30f : sv + 0.5f * (float)(jl - il);
      sacc[s][tt] = sv;
      tmax[tt] = fmaxf(tmax[tt], sv);
    }
#pragma unroll
  for (int tt = 0; tt < 4; ++tt) {
    float v = tmax[tt];
    v = fmaxf(v, __shfl_xor(v, 1, 64));
    v = fmaxf(v, __shfl_xor(v, 2, 64));
    v = fmaxf(v, __shfl_xor(v, 4, 64));
    v = fmaxf(v, __shfl_xor(v, 8, 64));
    tmax[tt] = v;
  }
  if (c == 0) {
#pragma unroll
    for (int tt = 0; tt < 4; ++tt) lm[h][4 * q + tt] = tmax[tt];
  }
  __syncthreads();  // 2-wave barrier (also drains vf0 prefetch)

  // ---- global max, p = exp(s-m), P -> LDS, partial sums ----
  float m[4];
#pragma unroll
  for (int tt = 0; tt < 4; ++tt)
    m[tt] = fmaxf(lm[0][4 * q + tt], lm[1][4 * q + tt]);

  float rsum[4] = {0.f, 0.f, 0.f, 0.f};
#pragma unroll
  for (int s = 0; s < 2; ++s)
#pragma unroll
    for (int tt = 0; tt < 4; ++tt) {
      const float p = __expf(sacc[s][tt] - m[tt]);
      rsum[tt] += p;
      pls[(4 * q + tt) * PLD + (2 * h + s) * 16 + c] = bf16r(p);
    }
#pragma unroll
  for (int tt = 0; tt < 4; ++tt) {
    float v = rsum[tt];
    v += __shfl_xor(v, 1, 64);
    v += __shfl_xor(v, 2, 64);
    v += __shfl_xor(v, 4, 64);
    v += __shfl_xor(v, 8, 64);
    rsum[tt] = v;
  }
  if (c == 0) {
#pragma unroll
    for (int tt = 0; tt < 4; ++tt) ls[h][4 * q + tt] = rsum[tt];
  }
  __syncthreads();  // 2-wave barrier

  float l[4];
#pragma unroll
  for (int tt = 0; tt < 4; ++tt)
    l[tt] = ls[0][4 * q + tt] + ls[1][4 * q + tt];

  // ---- O = P V for D-half h (dims h*256 .. +255), 64 keys ----
  float4v oacc[16];
#pragma unroll
  for (int dt = 0; dt < 16; ++dt) oacc[dt] = (float4v){0.f, 0.f, 0.f, 0.f};

  // chunk 0: V already resident in vf0
  if (ch0) {
    const short8 pa = *(const short8*)&pls[c * PLD + q * 8];
#pragma unroll
    for (int dt = 0; dt < 16; ++dt)
      oacc[dt] = __builtin_amdgcn_mfma_f32_16x16x32_bf16(pa, vf0[dt], oacc[dt], 0, 0, 0);
  }
  // chunk 1: loads overlap chunk-0 MFMAs (no barrier between)
  {
    const short8 pa = *(const short8*)&pls[c * PLD + 32 + q * 8];
    int kk = jb + 32 + q * 8;
    if (kk < 0) kk = 0;  // p == 0 there
    const unsigned short* vb = vbase + kk;
#pragma unroll
    for (int dt = 0; dt < 16; ++dt) {
      const short8 vf = *(const short8*)(vb + (size_t)dt * 16 * BS);
      oacc[dt] = __builtin_amdgcn_mfma_f32_16x16x32_bf16(pa, vf, oacc[dt], 0, 0, 0);
    }
  }

  // ---- epilogue: O / l ----
  float inv[4];
#pragma unroll
  for (int tt = 0; tt < 4; ++tt) inv[tt] = 1.0f / l[tt];
#pragma unroll
  for (int dt = 0; dt < 16; ++dt)
#pragma unroll
    for (int tt = 0; tt < 4; ++tt)
      out[(size_t)(r0 + 4 * q + tt) * D_MODEL + h * 256 + dt * 16 + c] =
          oacc[dt][tt] * inv[tt];
}

// --------------------------------------------------------------------------
extern "C" void kernel_launch(void* const* d_in, const int* in_sizes, int n_in,
                              void* d_out, int out_size, void* d_ws,
                              size_t ws_size, hipStream_t stream) {
  const float* x   = (const float*)d_in[0];
  const float* Wqk = (const float*)d_in[1];
  const float* Wv  = (const float*)d_in[2];
  const float* bv  = (const float*)d_in[3];
  float* out = (float*)d_out;

  unsigned short* xb   = (unsigned short*)d_ws;                  // 16 MB
  unsigned short* Qb   = xb + (size_t)BS * D_MODEL;              // 16 MB
  unsigned short* Vt   = Qb + (size_t)BS * D_MODEL;              // 16 MB
  unsigned short* Wqkt = Vt + (size_t)BS * D_MODEL;              // 512 KB
  unsigned short* Wvb  = Wqkt + (size_t)D_MODEL * D_MODEL;       // 512 KB
  unsigned short* xbB  = Wvb + (size_t)D_MODEL * D_MODEL;        // 16 MB

  const float scale = 1.0f / sqrtf((float)D_MODEL);

  cvt_w<<<dim3(256), dim3(256), 0, stream>>>(Wqk, Wqkt, Wv, Wvb, x, xb, xbB);
  qv_gemm<<<dim3(256), dim3(512), 0, stream>>>(xbB, Wqkt, Wvb, bv, Qb, Vt, scale);
  attn_tile<<<dim3(BS / 16), dim3(128), 0, stream>>>(Qb, xb, Vt, out);
}